// Round 1
// baseline (974.420 us; speedup 1.0000x reference)
//
#include <hip/hip_runtime.h>
#include <hip/hip_bf16.h>
#include <math.h>

// MIL_Cluster_FC: grouped expert MLP + masked mean pool + gated attention tail.
// Round 1: fp32 correctness-first scaffold.
//   - route each instance only through its own cluster's expert (10x less work
//     than the reference's masked formulation)
//   - device-side bucketing (hist -> aligned offsets -> scatter)
//   - fp32 tiled grouped GEMMs (64x64 tile, 4x4 per thread)
//   - GEMM2 fuses relu + masked column-sum (atomic) into pooled
//   - single-block tail for the [10,512] -> [1,4] attention/classifier chain

#define C_NUM 10
#define D_IN 1024
#define D_H 512
#define D_ATT 256
#define N_CLS 4
#define TM 64
#define TN 64
#define BK 16

__global__ void k_init(int* counts, int* cursor, int* bucket, float* pooled, int npad) {
    int i = blockIdx.x * blockDim.x + threadIdx.x;
    if (i < npad) bucket[i] = -1;
    if (i < C_NUM * D_H) pooled[i] = 0.f;
    if (i < 16) { counts[i] = 0; cursor[i] = 0; }
}

__global__ void k_hist(const int* __restrict__ cid, int* counts, int n) {
    int i = blockIdx.x * blockDim.x + threadIdx.x;
    if (i < n) atomicAdd(&counts[cid[i]], 1);
}

__global__ void k_offsets(const int* __restrict__ counts, int* aoff) {
    if (threadIdx.x == 0) {
        int off = 0;
        for (int c = 0; c < C_NUM; ++c) {
            aoff[c] = off;
            off += ((counts[c] + TM - 1) / TM) * TM;  // TM-aligned regions
        }
        aoff[C_NUM] = off;
    }
}

__global__ void k_scatter(const int* __restrict__ cid, int* cursor,
                          const int* __restrict__ aoff, int* bucket, int n) {
    int i = blockIdx.x * blockDim.x + threadIdx.x;
    if (i < n) {
        int c = cid[i];
        int pos = atomicAdd(&cursor[c], 1);
        bucket[aoff[c] + pos] = i;
    }
}

// h1[r,:] = relu(x[bucket[r],:] @ W1[c] + b1[c]), 0 for pad rows
__global__ __launch_bounds__(256) void k_gemm1(
    const float* __restrict__ x, const float* __restrict__ W1, const float* __restrict__ b1,
    const int* __restrict__ bucket, const int* __restrict__ aoff,
    float* __restrict__ h1)
{
    int rowStart = blockIdx.x * TM;
    if (rowStart >= aoff[C_NUM]) return;
    int c = 0;
    while (c < C_NUM - 1 && rowStart >= aoff[c + 1]) ++c;
    int colStart = blockIdx.y * TN;
    const float* __restrict__ W = W1 + (size_t)c * D_IN * D_H;

    __shared__ float As[TM][BK + 1];
    __shared__ float Bs[BK][TN];
    __shared__ int ridx[TM];

    int tid = threadIdx.x;
    if (tid < TM) ridx[tid] = bucket[rowStart + tid];
    __syncthreads();

    int tx = tid & 15, ty = tid >> 4;
    float acc[4][4] = {};

    for (int k0 = 0; k0 < D_IN; k0 += BK) {
#pragma unroll
        for (int i = 0; i < 4; ++i) {
            int m = (tid >> 4) + 16 * i;
            int k = tid & 15;
            int r = ridx[m];
            As[m][k] = (r >= 0) ? x[(size_t)r * D_IN + k0 + k] : 0.f;
        }
#pragma unroll
        for (int i = 0; i < 4; ++i) {
            int nn = tid & 63;
            int k = (tid >> 6) + 4 * i;
            Bs[k][nn] = W[(size_t)(k0 + k) * D_H + colStart + nn];
        }
        __syncthreads();
#pragma unroll
        for (int k = 0; k < BK; ++k) {
            float ra[4], rb[4];
#pragma unroll
            for (int i = 0; i < 4; ++i) ra[i] = As[ty + 16 * i][k];
#pragma unroll
            for (int j = 0; j < 4; ++j) rb[j] = Bs[k][tx + 16 * j];
#pragma unroll
            for (int i = 0; i < 4; ++i)
#pragma unroll
                for (int j = 0; j < 4; ++j)
                    acc[i][j] += ra[i] * rb[j];
        }
        __syncthreads();
    }

#pragma unroll
    for (int i = 0; i < 4; ++i) {
        int m = ty + 16 * i;
        int gm = rowStart + m;
        bool real = (ridx[m] >= 0);
#pragma unroll
        for (int j = 0; j < 4; ++j) {
            int col = colStart + tx + 16 * j;
            float v = real ? fmaxf(acc[i][j] + b1[c * D_H + col], 0.f) : 0.f;
            h1[(size_t)gm * D_H + col] = v;
        }
    }
}

// pooled[c,:] += column-sum over real rows of relu(h1 @ W2[c] + b2[c])
__global__ __launch_bounds__(256) void k_gemm2(
    const float* __restrict__ h1, const float* __restrict__ W2, const float* __restrict__ b2,
    const int* __restrict__ bucket, const int* __restrict__ aoff,
    float* __restrict__ pooled)
{
    int rowStart = blockIdx.x * TM;
    if (rowStart >= aoff[C_NUM]) return;
    int c = 0;
    while (c < C_NUM - 1 && rowStart >= aoff[c + 1]) ++c;
    int colStart = blockIdx.y * TN;
    const float* __restrict__ W = W2 + (size_t)c * D_H * D_H;

    __shared__ float As[TM][BK + 1];
    __shared__ float Bs[BK][TN];
    __shared__ float red[16][TN];
    __shared__ int ridx[TM];

    int tid = threadIdx.x;
    if (tid < TM) ridx[tid] = bucket[rowStart + tid];
    __syncthreads();

    int tx = tid & 15, ty = tid >> 4;
    float acc[4][4] = {};

    for (int k0 = 0; k0 < D_H; k0 += BK) {
#pragma unroll
        for (int i = 0; i < 4; ++i) {
            int m = (tid >> 4) + 16 * i;
            int k = tid & 15;
            As[m][k] = h1[(size_t)(rowStart + m) * D_H + k0 + k];
        }
#pragma unroll
        for (int i = 0; i < 4; ++i) {
            int nn = tid & 63;
            int k = (tid >> 6) + 4 * i;
            Bs[k][nn] = W[(size_t)(k0 + k) * D_H + colStart + nn];
        }
        __syncthreads();
#pragma unroll
        for (int k = 0; k < BK; ++k) {
            float ra[4], rb[4];
#pragma unroll
            for (int i = 0; i < 4; ++i) ra[i] = As[ty + 16 * i][k];
#pragma unroll
            for (int j = 0; j < 4; ++j) rb[j] = Bs[k][tx + 16 * j];
#pragma unroll
            for (int i = 0; i < 4; ++i)
#pragma unroll
                for (int j = 0; j < 4; ++j)
                    acc[i][j] += ra[i] * rb[j];
        }
        __syncthreads();
    }

    float colsum[4] = {0.f, 0.f, 0.f, 0.f};
#pragma unroll
    for (int i = 0; i < 4; ++i) {
        int m = ty + 16 * i;
        if (ridx[m] >= 0) {
#pragma unroll
            for (int j = 0; j < 4; ++j) {
                int col = colStart + tx + 16 * j;
                colsum[j] += fmaxf(acc[i][j] + b2[c * D_H + col], 0.f);
            }
        }
    }
#pragma unroll
    for (int j = 0; j < 4; ++j) red[ty][tx + 16 * j] = colsum[j];
    __syncthreads();
    if (tid < TN) {
        float s = 0.f;
#pragma unroll
        for (int t = 0; t < 16; ++t) s += red[t][tid];
        atomicAdd(&pooled[c * D_H + colStart + tid], s);
    }
}

__global__ __launch_bounds__(512) void k_tail(
    const float* __restrict__ pooled, const int* __restrict__ counts,
    const float* __restrict__ Wfc, const float* __restrict__ bfc,
    const float* __restrict__ Wa, const float* __restrict__ ba,
    const float* __restrict__ Wb, const float* __restrict__ bb,
    const float* __restrict__ Wc, const float* __restrict__ bc,
    const float* __restrict__ Wrho, const float* __restrict__ brho,
    const float* __restrict__ Wcls, const float* __restrict__ bcls,
    float* __restrict__ out)
{
    __shared__ float hc[C_NUM][D_H];
    __shared__ float hfc[C_NUM][D_H];
    __shared__ float red[512];
    __shared__ float sc[C_NUM];
    __shared__ float sA[C_NUM];
    __shared__ float hp[D_H];
    __shared__ float hr[D_ATT];
    int tid = threadIdx.x;

    for (int idx = tid; idx < C_NUM * D_H; idx += 512) {
        int c = idx >> 9, j = idx & 511;
        float cnt = fmaxf((float)counts[c], 1.f);
        hc[c][j] = pooled[idx] / cnt;
    }
    __syncthreads();

    // fc: hfc = relu(hc @ Wfc + bfc)
    {
        int j = tid;  // 0..511
        for (int c = 0; c < C_NUM; ++c) {
            float acc = bfc[j];
            for (int k = 0; k < D_H; ++k) acc += hc[c][k] * Wfc[k * D_H + j];
            hfc[c][j] = fmaxf(acc, 0.f);
        }
    }
    __syncthreads();

    // gated attention scores per cluster
    for (int c = 0; c < C_NUM; ++c) {
        float val = 0.f;
        if (tid < D_ATT) {
            float sa = ba[tid], sb = bb[tid];
            for (int k = 0; k < D_H; ++k) {
                float h = hfc[c][k];
                sa += h * Wa[k * D_ATT + tid];
                sb += h * Wb[k * D_ATT + tid];
            }
            float ta = tanhf(sa);
            float sg = 1.f / (1.f + expf(-sb));
            val = ta * sg * Wc[tid];
        }
        red[tid] = val;
        __syncthreads();
        for (int s = 256; s > 0; s >>= 1) {
            if (tid < s) red[tid] += red[tid + s];
            __syncthreads();
        }
        if (tid == 0) sc[c] = red[0] + bc[0];
        __syncthreads();
    }

    // softmax over clusters
    if (tid == 0) {
        float mx = sc[0];
        for (int c = 1; c < C_NUM; ++c) mx = fmaxf(mx, sc[c]);
        float sum = 0.f;
        for (int c = 0; c < C_NUM; ++c) { float e = expf(sc[c] - mx); sA[c] = e; sum += e; }
        for (int c = 0; c < C_NUM; ++c) sA[c] /= sum;
    }
    __syncthreads();

    // h_path = A @ hfc
    {
        float s = 0.f;
        for (int c = 0; c < C_NUM; ++c) s += sA[c] * hfc[c][tid];
        hp[tid] = s;
    }
    __syncthreads();

    // rho
    if (tid < D_ATT) {
        float acc = brho[tid];
        for (int k = 0; k < D_H; ++k) acc += hp[k] * Wrho[k * D_ATT + tid];
        hr[tid] = fmaxf(acc, 0.f);
    }
    __syncthreads();

    // classifier + hazards / survival / argmax
    if (tid == 0) {
        float lg[N_CLS];
        for (int l = 0; l < N_CLS; ++l) {
            float acc = bcls[l];
            for (int k = 0; k < D_ATT; ++k) acc += hr[k] * Wcls[k * N_CLS + l];
            lg[l] = acc;
        }
        int best = 0;
        for (int l = 1; l < N_CLS; ++l) if (lg[l] > lg[best]) best = l;
        float Sv = 1.f;
        for (int l = 0; l < N_CLS; ++l) {
            float hz = 1.f / (1.f + expf(-lg[l]));
            out[l] = hz;
            Sv *= (1.f - hz);
            out[4 + l] = Sv;
        }
        out[8] = (float)best;
    }
}

extern "C" void kernel_launch(void* const* d_in, const int* in_sizes, int n_in,
                              void* d_out, int out_size, void* d_ws, size_t ws_size,
                              hipStream_t stream)
{
    const float* x    = (const float*)d_in[0];
    const int*   cid  = (const int*)d_in[1];
    const float* W1   = (const float*)d_in[2];
    const float* b1   = (const float*)d_in[3];
    const float* W2   = (const float*)d_in[4];
    const float* b2   = (const float*)d_in[5];
    const float* Wfc  = (const float*)d_in[6];
    const float* bfc  = (const float*)d_in[7];
    const float* Wa   = (const float*)d_in[8];
    const float* ba   = (const float*)d_in[9];
    const float* Wb   = (const float*)d_in[10];
    const float* bb   = (const float*)d_in[11];
    const float* Wc   = (const float*)d_in[12];
    const float* bc   = (const float*)d_in[13];
    const float* Wrho = (const float*)d_in[14];
    const float* brho = (const float*)d_in[15];
    const float* Wcls = (const float*)d_in[16];
    const float* bcls = (const float*)d_in[17];
    float* out = (float*)d_out;

    int n = in_sizes[0] / D_IN;                               // 20000
    int rowTilesMax = (n + C_NUM * (TM - 1) + TM - 1) / TM;   // 323
    int npad = rowTilesMax * TM;                              // 20672

    // workspace layout (needs ~42.5 MB)
    char* w = (char*)d_ws;
    int* counts = (int*)w;                    // [16]
    int* cursor = counts + 16;                // [16]
    int* aoff   = cursor + 16;                // [11] (padded to 16)
    int* bucket = aoff + 16;                  // [npad]
    float* pooled = (float*)(bucket + npad);  // [C_NUM * D_H]
    float* h1 = pooled + C_NUM * D_H;         // [npad * D_H]

    int ib = (npad + 255) / 256;
    k_init<<<ib, 256, 0, stream>>>(counts, cursor, bucket, pooled, npad);
    int nb = (n + 255) / 256;
    k_hist<<<nb, 256, 0, stream>>>(cid, counts, n);
    k_offsets<<<1, 64, 0, stream>>>(counts, aoff);
    k_scatter<<<nb, 256, 0, stream>>>(cid, cursor, aoff, bucket, n);

    dim3 g(rowTilesMax, D_H / TN);
    k_gemm1<<<g, 256, 0, stream>>>(x, W1, b1, bucket, aoff, h1);
    k_gemm2<<<g, 256, 0, stream>>>(h1, W2, b2, bucket, aoff, pooled);

    k_tail<<<1, 512, 0, stream>>>(pooled, counts, Wfc, bfc, Wa, ba, Wb, bb,
                                  Wc, bc, Wrho, brho, Wcls, bcls, out);
}

// Round 2
// 394.273 us; speedup vs baseline: 2.4714x; 2.4714x over previous
//
#include <hip/hip_runtime.h>
#include <hip/hip_bf16.h>
#include <math.h>

// MIL_Cluster_FC round 2: bf16 MFMA grouped GEMMs.
//  - W1/W2 pre-transposed+converted to bf16 [C][N][K] (k-contiguous B operand)
//  - 128x128 tile, BK=64, 4 waves (2x2), mfma_f32_16x16x32_bf16, 4x4 frags/wave
//  - LDS layout [row][k] with 16B-slot XOR swizzle (slot ^= row&7) -> minimal
//    bank aliasing on ds_read_b128; global_load_lds staged with pre-swizzled
//    global source (linear LDS dest), reg-staged cvt path for fp32 x
//  - gemm2 fuses bias+relu+row-mask+column-sum (shfl reduce + atomicAdd)

#define C_NUM 10
#define D_IN 1024
#define D_H 512
#define D_ATT 256
#define N_CLS 4
#define BM 128
#define BN 128
#define BKS 64

typedef __attribute__((ext_vector_type(8))) short short8v;
typedef __attribute__((ext_vector_type(4))) short short4v;
typedef __attribute__((ext_vector_type(4))) float f32x4;

__device__ __forceinline__ short f2bf(float f) {
    __hip_bfloat16 h = __float2bfloat16(f);
    return *reinterpret_cast<short*>(&h);
}

__device__ __forceinline__ void gload_lds16(const void* g, void* l) {
    __builtin_amdgcn_global_load_lds((const __attribute__((address_space(1))) unsigned int*)g,
                                     (__attribute__((address_space(3))) unsigned int*)l,
                                     16, 0, 0);
}

__global__ void k_init(int* counts, int* cursor, int* bucket, float* pooled, int npad) {
    int i = blockIdx.x * blockDim.x + threadIdx.x;
    if (i < npad) bucket[i] = -1;
    if (i < C_NUM * D_H) pooled[i] = 0.f;
    if (i < 16) { counts[i] = 0; cursor[i] = 0; }
}

__global__ void k_hist(const int* __restrict__ cid, int* counts, int n) {
    int i = blockIdx.x * blockDim.x + threadIdx.x;
    if (i < n) atomicAdd(&counts[cid[i]], 1);
}

__global__ void k_offsets(const int* __restrict__ counts, int* aoff) {
    if (threadIdx.x == 0) {
        int off = 0;
        for (int c = 0; c < C_NUM; ++c) {
            aoff[c] = off;
            off += ((counts[c] + BM - 1) / BM) * BM;  // BM-aligned regions
        }
        aoff[C_NUM] = off;
    }
}

__global__ void k_scatter(const int* __restrict__ cid, int* cursor,
                          const int* __restrict__ aoff, int* bucket, int n) {
    int i = blockIdx.x * blockDim.x + threadIdx.x;
    if (i < n) {
        int c = cid[i];
        int pos = atomicAdd(&cursor[c], 1);
        bucket[aoff[c] + pos] = i;
    }
}

// W [C][K][N] fp32 -> Wt [C][N][K] bf16.  grid (K/64, N/64, C), block 256.
__global__ __launch_bounds__(256) void k_transpose(const float* __restrict__ W,
                                                   short* __restrict__ Wt, int K, int N) {
    __shared__ float t[64][65];
    int k0 = blockIdx.x * 64, n0 = blockIdx.y * 64, cc = blockIdx.z;
    const float* src = W + (size_t)cc * K * N;
    short* dst = Wt + (size_t)cc * N * K;
    int tid = threadIdx.x;
    int tk = tid >> 4, tn4 = (tid & 15) * 4;
#pragma unroll
    for (int it = 0; it < 4; ++it) {
        int k = tk + it * 16;
        f32x4 v = *(const f32x4*)&src[(size_t)(k0 + k) * N + n0 + tn4];
        t[k][tn4 + 0] = v[0]; t[k][tn4 + 1] = v[1];
        t[k][tn4 + 2] = v[2]; t[k][tn4 + 3] = v[3];
    }
    __syncthreads();
    int wn = tid >> 2, kq = (tid & 3) * 16;
#pragma unroll
    for (int q = 0; q < 4; ++q) {
        int k = kq + q * 4;
        short4v o;
#pragma unroll
        for (int e = 0; e < 4; ++e) o[e] = f2bf(t[k + e][wn]);
        *(short4v*)&dst[(size_t)(n0 + wn) * K + k0 + k] = o;
    }
}

// h1[r,:] = relu(x[bucket[r],:] @ W1[c] + b1[c]) in bf16; 0 for pad rows
__global__ __launch_bounds__(256) void k_gemm1_mfma(
    const float* __restrict__ x, const short* __restrict__ Wt, const float* __restrict__ b1,
    const int* __restrict__ bucket, const int* __restrict__ aoff, short* __restrict__ h1)
{
    __shared__ short As[BM * BKS];
    __shared__ short Bs[BN * BKS];
    __shared__ int ridx[BM];

    int rowStart = blockIdx.x * BM;
    if (rowStart >= aoff[C_NUM]) return;
    int c = 0;
    while (c < C_NUM - 1 && rowStart >= aoff[c + 1]) ++c;
    int colStart = blockIdx.y * BN;

    int tid = threadIdx.x;
    int lane = tid & 63;
    int wid = tid >> 6;
    int wm = wid >> 1, wn = wid & 1;

    if (tid < BM) ridx[tid] = bucket[rowStart + tid];
    __syncthreads();

    // A staging: 2 threads/row, 32 floats each
    int arow = tid >> 1;
    int khalf = tid & 1;
    int agr = ridx[arow];
    const float* aptr = x + (size_t)(agr < 0 ? 0 : agr) * D_IN + khalf * 32;

    // B staging via global_load_lds, pre-swizzled source slot
    int l8 = lane >> 3;
    int sslot = (lane & 7) ^ l8;
    const short* bbase = Wt + ((size_t)c * D_H + colStart + l8) * D_IN + sslot * 8;

    f32x4 acc[4][4];
#pragma unroll
    for (int i = 0; i < 4; ++i)
#pragma unroll
        for (int j = 0; j < 4; ++j)
            acc[i][j] = f32x4{0.f, 0.f, 0.f, 0.f};

    for (int k0 = 0; k0 < D_IN; k0 += BKS) {
#pragma unroll
        for (int q = 0; q < 4; ++q) {
            int nbase = (q * 4 + wid) * 8;
            gload_lds16(bbase + (size_t)nbase * D_IN + k0, &Bs[nbase * BKS]);
        }
        {
            const f32x4* p = (const f32x4*)(aptr + k0);
#pragma unroll
            for (int q = 0; q < 4; ++q) {
                f32x4 f0 = {0.f, 0.f, 0.f, 0.f}, f1 = {0.f, 0.f, 0.f, 0.f};
                if (agr >= 0) { f0 = p[2 * q]; f1 = p[2 * q + 1]; }
                short8v v;
#pragma unroll
                for (int e = 0; e < 4; ++e) { v[e] = f2bf(f0[e]); v[4 + e] = f2bf(f1[e]); }
                int slot = (khalf * 4 + q) ^ (arow & 7);
                *(short8v*)&As[arow * BKS + slot * 8] = v;
            }
        }
        __syncthreads();
#pragma unroll
        for (int kk = 0; kk < 2; ++kk) {
            short8v af[4], bfr[4];
#pragma unroll
            for (int i = 0; i < 4; ++i) {
                int row = wm * 64 + i * 16 + (lane & 15);
                int slot = (kk * 4 + (lane >> 4)) ^ (row & 7);
                af[i] = *(const short8v*)&As[row * BKS + slot * 8];
            }
#pragma unroll
            for (int j = 0; j < 4; ++j) {
                int nn = wn * 64 + j * 16 + (lane & 15);
                int slot = (kk * 4 + (lane >> 4)) ^ (nn & 7);
                bfr[j] = *(const short8v*)&Bs[nn * BKS + slot * 8];
            }
#pragma unroll
            for (int i = 0; i < 4; ++i)
#pragma unroll
                for (int j = 0; j < 4; ++j)
                    acc[i][j] = __builtin_amdgcn_mfma_f32_16x16x32_bf16(af[i], bfr[j], acc[i][j], 0, 0, 0);
        }
        __syncthreads();
    }

    const float* bias = b1 + c * D_H;
    float bj[4];
#pragma unroll
    for (int j = 0; j < 4; ++j) bj[j] = bias[colStart + wn * 64 + j * 16 + (lane & 15)];
#pragma unroll
    for (int i = 0; i < 4; ++i) {
#pragma unroll
        for (int r = 0; r < 4; ++r) {
            int rowl = wm * 64 + i * 16 + (lane >> 4) * 4 + r;
            bool valid = (ridx[rowl] >= 0);
            size_t gro = (size_t)(rowStart + rowl) * D_H + colStart + wn * 64 + (lane & 15);
#pragma unroll
            for (int j = 0; j < 4; ++j) {
                float v = valid ? fmaxf(acc[i][j][r] + bj[j], 0.f) : 0.f;
                h1[gro + j * 16] = f2bf(v);
            }
        }
    }
}

// pooled[c,:] += column-sum over real rows of relu(h1 @ W2[c] + b2[c])
__global__ __launch_bounds__(256) void k_gemm2_mfma(
    const short* __restrict__ h1, const short* __restrict__ Wt, const float* __restrict__ b2,
    const int* __restrict__ bucket, const int* __restrict__ aoff, float* __restrict__ pooled)
{
    __shared__ short As[BM * BKS];
    __shared__ short Bs[BN * BKS];
    __shared__ int ridx[BM];

    int rowStart = blockIdx.x * BM;
    if (rowStart >= aoff[C_NUM]) return;
    int c = 0;
    while (c < C_NUM - 1 && rowStart >= aoff[c + 1]) ++c;
    int colStart = blockIdx.y * BN;

    int tid = threadIdx.x;
    int lane = tid & 63;
    int wid = tid >> 6;
    int wm = wid >> 1, wn = wid & 1;

    if (tid < BM) ridx[tid] = bucket[rowStart + tid];

    int l8 = lane >> 3;
    int sslot = (lane & 7) ^ l8;
    const short* abase = h1 + (size_t)(rowStart + l8) * D_H + sslot * 8;
    const short* bbase = Wt + ((size_t)c * D_H + colStart + l8) * D_H + sslot * 8;

    f32x4 acc[4][4];
#pragma unroll
    for (int i = 0; i < 4; ++i)
#pragma unroll
        for (int j = 0; j < 4; ++j)
            acc[i][j] = f32x4{0.f, 0.f, 0.f, 0.f};

    for (int k0 = 0; k0 < D_H; k0 += BKS) {
#pragma unroll
        for (int q = 0; q < 4; ++q) {
            int rb = (q * 4 + wid) * 8;
            gload_lds16(abase + (size_t)rb * D_H + k0, &As[rb * BKS]);
            gload_lds16(bbase + (size_t)rb * D_H + k0, &Bs[rb * BKS]);
        }
        __syncthreads();
#pragma unroll
        for (int kk = 0; kk < 2; ++kk) {
            short8v af[4], bfr[4];
#pragma unroll
            for (int i = 0; i < 4; ++i) {
                int row = wm * 64 + i * 16 + (lane & 15);
                int slot = (kk * 4 + (lane >> 4)) ^ (row & 7);
                af[i] = *(const short8v*)&As[row * BKS + slot * 8];
            }
#pragma unroll
            for (int j = 0; j < 4; ++j) {
                int nn = wn * 64 + j * 16 + (lane & 15);
                int slot = (kk * 4 + (lane >> 4)) ^ (nn & 7);
                bfr[j] = *(const short8v*)&Bs[nn * BKS + slot * 8];
            }
#pragma unroll
            for (int i = 0; i < 4; ++i)
#pragma unroll
                for (int j = 0; j < 4; ++j)
                    acc[i][j] = __builtin_amdgcn_mfma_f32_16x16x32_bf16(af[i], bfr[j], acc[i][j], 0, 0, 0);
        }
        __syncthreads();
    }

    const float* bias = b2 + c * D_H;
    float bj[4];
#pragma unroll
    for (int j = 0; j < 4; ++j) bj[j] = bias[colStart + wn * 64 + j * 16 + (lane & 15)];
    float csum[4] = {0.f, 0.f, 0.f, 0.f};
#pragma unroll
    for (int i = 0; i < 4; ++i) {
#pragma unroll
        for (int r = 0; r < 4; ++r) {
            int rowl = wm * 64 + i * 16 + (lane >> 4) * 4 + r;
            float m = (ridx[rowl] >= 0) ? 1.f : 0.f;
#pragma unroll
            for (int j = 0; j < 4; ++j)
                csum[j] += m * fmaxf(acc[i][j][r] + bj[j], 0.f);
        }
    }
#pragma unroll
    for (int j = 0; j < 4; ++j) {
        float s = csum[j];
        s += __shfl_xor(s, 16, 64);
        s += __shfl_xor(s, 32, 64);
        if ((lane >> 4) == 0)
            atomicAdd(&pooled[c * D_H + colStart + wn * 64 + j * 16 + lane], s);
    }
}

__global__ __launch_bounds__(512) void k_tail(
    const float* __restrict__ pooled, const int* __restrict__ counts,
    const float* __restrict__ Wfc, const float* __restrict__ bfc,
    const float* __restrict__ Wa, const float* __restrict__ ba,
    const float* __restrict__ Wb, const float* __restrict__ bb,
    const float* __restrict__ Wc, const float* __restrict__ bc,
    const float* __restrict__ Wrho, const float* __restrict__ brho,
    const float* __restrict__ Wcls, const float* __restrict__ bcls,
    float* __restrict__ out)
{
    __shared__ float hc[C_NUM][D_H];
    __shared__ float hfc[C_NUM][D_H];
    __shared__ float sA[C_NUM];
    __shared__ float hp[D_H];
    __shared__ float hr[D_ATT];
    __shared__ float part[4][C_NUM];
    __shared__ float cpart[4][N_CLS];
    int tid = threadIdx.x, lane = tid & 63, w = tid >> 6;

    for (int idx = tid; idx < C_NUM * D_H; idx += 512) {
        int cc = idx >> 9, j = idx & (D_H - 1);
        hc[cc][j] = pooled[idx] / fmaxf((float)counts[cc], 1.f);
    }
    __syncthreads();

    {   // fc layer: all 512 threads, accumulator array over clusters
        float accs[C_NUM];
        float bv = bfc[tid];
#pragma unroll
        for (int cc = 0; cc < C_NUM; ++cc) accs[cc] = bv;
        for (int k = 0; k < D_H; ++k) {
            float wv = Wfc[(size_t)k * D_H + tid];
#pragma unroll
            for (int cc = 0; cc < C_NUM; ++cc) accs[cc] += hc[cc][k] * wv;
        }
#pragma unroll
        for (int cc = 0; cc < C_NUM; ++cc) hfc[cc][tid] = fmaxf(accs[cc], 0.f);
    }
    __syncthreads();

    if (tid < D_ATT) {  // gated attention scores
        float sa[C_NUM], sb[C_NUM];
        float bav = ba[tid], bbv = bb[tid];
#pragma unroll
        for (int cc = 0; cc < C_NUM; ++cc) { sa[cc] = bav; sb[cc] = bbv; }
        for (int k = 0; k < D_H; ++k) {
            float wav = Wa[(size_t)k * D_ATT + tid];
            float wbv = Wb[(size_t)k * D_ATT + tid];
#pragma unroll
            for (int cc = 0; cc < C_NUM; ++cc) {
                sa[cc] += hfc[cc][k] * wav;
                sb[cc] += hfc[cc][k] * wbv;
            }
        }
        float wcv = Wc[tid];
#pragma unroll
        for (int cc = 0; cc < C_NUM; ++cc) {
            float v = tanhf(sa[cc]) * (1.f / (1.f + expf(-sb[cc]))) * wcv;
            v += __shfl_xor(v, 1, 64); v += __shfl_xor(v, 2, 64); v += __shfl_xor(v, 4, 64);
            v += __shfl_xor(v, 8, 64); v += __shfl_xor(v, 16, 64); v += __shfl_xor(v, 32, 64);
            if (lane == 0) part[w][cc] = v;
        }
    }
    __syncthreads();
    if (tid == 0) {  // softmax over clusters
        float sc2[C_NUM];
        float mx = -1e30f;
#pragma unroll
        for (int cc = 0; cc < C_NUM; ++cc) {
            sc2[cc] = part[0][cc] + part[1][cc] + part[2][cc] + part[3][cc] + bc[0];
            mx = fmaxf(mx, sc2[cc]);
        }
        float sum = 0.f;
#pragma unroll
        for (int cc = 0; cc < C_NUM; ++cc) { sc2[cc] = expf(sc2[cc] - mx); sum += sc2[cc]; }
#pragma unroll
        for (int cc = 0; cc < C_NUM; ++cc) sA[cc] = sc2[cc] / sum;
    }
    __syncthreads();
    {   // h_path = A @ hfc
        float s = 0.f;
#pragma unroll
        for (int cc = 0; cc < C_NUM; ++cc) s += sA[cc] * hfc[cc][tid];
        hp[tid] = s;
    }
    __syncthreads();
    if (tid < D_ATT) {  // rho
        float a2 = brho[tid];
        for (int k = 0; k < D_H; ++k) a2 += hp[k] * Wrho[(size_t)k * D_ATT + tid];
        hr[tid] = fmaxf(a2, 0.f);
    }
    __syncthreads();
    if (tid < D_ATT) {  // classifier partials
        f32x4 wv = *(const f32x4*)&Wcls[tid * N_CLS];
        float h = hr[tid];
        float v[N_CLS];
#pragma unroll
        for (int l = 0; l < N_CLS; ++l) {
            v[l] = h * wv[l];
            v[l] += __shfl_xor(v[l], 1, 64); v[l] += __shfl_xor(v[l], 2, 64);
            v[l] += __shfl_xor(v[l], 4, 64); v[l] += __shfl_xor(v[l], 8, 64);
            v[l] += __shfl_xor(v[l], 16, 64); v[l] += __shfl_xor(v[l], 32, 64);
        }
        if (lane == 0) {
#pragma unroll
            for (int l = 0; l < N_CLS; ++l) cpart[w][l] = v[l];
        }
    }
    __syncthreads();
    if (tid == 0) {
        float lg[N_CLS];
#pragma unroll
        for (int l = 0; l < N_CLS; ++l)
            lg[l] = cpart[0][l] + cpart[1][l] + cpart[2][l] + cpart[3][l] + bcls[l];
        int best = 0;
#pragma unroll
        for (int l = 1; l < N_CLS; ++l) if (lg[l] > lg[best]) best = l;
        float Sv = 1.f;
#pragma unroll
        for (int l = 0; l < N_CLS; ++l) {
            float hz = 1.f / (1.f + expf(-lg[l]));
            out[l] = hz;
            Sv *= (1.f - hz);
            out[4 + l] = Sv;
        }
        out[8] = (float)best;
    }
}

extern "C" void kernel_launch(void* const* d_in, const int* in_sizes, int n_in,
                              void* d_out, int out_size, void* d_ws, size_t ws_size,
                              hipStream_t stream)
{
    const float* x    = (const float*)d_in[0];
    const int*   cid  = (const int*)d_in[1];
    const float* W1   = (const float*)d_in[2];
    const float* b1   = (const float*)d_in[3];
    const float* W2   = (const float*)d_in[4];
    const float* b2   = (const float*)d_in[5];
    const float* Wfc  = (const float*)d_in[6];
    const float* bfc  = (const float*)d_in[7];
    const float* Wa   = (const float*)d_in[8];
    const float* ba   = (const float*)d_in[9];
    const float* Wb   = (const float*)d_in[10];
    const float* bb   = (const float*)d_in[11];
    const float* Wc   = (const float*)d_in[12];
    const float* bc   = (const float*)d_in[13];
    const float* Wrho = (const float*)d_in[14];
    const float* brho = (const float*)d_in[15];
    const float* Wcls = (const float*)d_in[16];
    const float* bcls = (const float*)d_in[17];
    float* out = (float*)d_out;

    int n = in_sizes[0] / D_IN;                        // 20000
    int rowTiles = (n + BM - 1) / BM + C_NUM;          // worst-case 128-aligned tiles
    int npadMax = rowTiles * BM;

    // workspace layout (~36 MB)
    char* w = (char*)d_ws;
    int* counts = (int*)w;                 // [16]
    int* cursor = counts + 16;             // [16]
    int* aoff   = counts + 32;             // [11]
    int* bucket = counts + 64;             // [npadMax]  @ 256B
    float* pooled = (float*)(w + 256 + (size_t)npadMax * 4);           // [C*512]
    short* Wt1 = (short*)((char*)pooled + (size_t)C_NUM * D_H * 4);    // [C][512][1024]
    short* Wt2 = Wt1 + (size_t)C_NUM * D_H * D_IN;                     // [C][512][512]
    short* h1  = Wt2 + (size_t)C_NUM * D_H * D_H;                      // [npadMax][512]

    int ib = (npadMax + 255) / 256;
    k_init<<<ib, 256, 0, stream>>>(counts, cursor, bucket, pooled, npadMax);
    int nb = (n + 255) / 256;
    k_hist<<<nb, 256, 0, stream>>>(cid, counts, n);
    k_offsets<<<1, 64, 0, stream>>>(counts, aoff);
    k_scatter<<<nb, 256, 0, stream>>>(cid, cursor, aoff, bucket, n);

    k_transpose<<<dim3(D_IN / 64, D_H / 64, C_NUM), 256, 0, stream>>>(W1, Wt1, D_IN, D_H);
    k_transpose<<<dim3(D_H / 64, D_H / 64, C_NUM), 256, 0, stream>>>(W2, Wt2, D_H, D_H);

    k_gemm1_mfma<<<dim3(rowTiles, D_H / BN), 256, 0, stream>>>(x, Wt1, b1, bucket, aoff, h1);
    k_gemm2_mfma<<<dim3(rowTiles, D_H / BN), 256, 0, stream>>>(h1, Wt2, b2, bucket, aoff, pooled);

    k_tail<<<1, 512, 0, stream>>>(pooled, counts, Wfc, bfc, Wa, ba, Wb, bb,
                                  Wc, bc, Wrho, brho, Wcls, bcls, out);
}

// Round 3
// 287.029 us; speedup vs baseline: 3.3948x; 1.3736x over previous
//
#include <hip/hip_runtime.h>
#include <hip/hip_bf16.h>
#include <math.h>

// MIL_Cluster_FC round 3:
//  - tail parallelized into 5 multi-block stages (was 181 us single-block)
//  - gemm1 A-operand pre-gathered+converted to bf16 (xb) -> global_load_lds
//    staging for both operands (ws_size-guarded, falls back to R2 path)
//  - bijective XCD-aware block swizzle on both GEMMs (column-sibling blocks
//    share an XCD L2 -> A panel fetched once)

#define C_NUM 10
#define D_IN 1024
#define D_H 512
#define D_ATT 256
#define N_CLS 4
#define BM 128
#define BN 128
#define BKS 64

typedef __attribute__((ext_vector_type(8))) short short8v;
typedef __attribute__((ext_vector_type(4))) short short4v;
typedef __attribute__((ext_vector_type(4))) float f32x4;

__device__ __forceinline__ short f2bf(float f) {
    __hip_bfloat16 h = __float2bfloat16(f);
    return *reinterpret_cast<short*>(&h);
}

__device__ __forceinline__ void gload_lds16(const void* g, void* l) {
    __builtin_amdgcn_global_load_lds((const __attribute__((address_space(1))) unsigned int*)g,
                                     (__attribute__((address_space(3))) unsigned int*)l,
                                     16, 0, 0);
}

// bijective XCD-chunked swizzle (m204): blocks with consecutive logical ids
// land on the same XCD
__device__ __forceinline__ int xcd_swizzle(int orig, int nwg) {
    int q = nwg >> 3, r = nwg & 7;
    int xcd = orig & 7, base = orig >> 3;
    return (xcd < r ? xcd * (q + 1) : r * (q + 1) + (xcd - r) * q) + base;
}

__global__ void k_init(int* counts, int* cursor, int* bucket, float* pooled,
                       float* scores, float* hr_raw, int npad) {
    int i = blockIdx.x * blockDim.x + threadIdx.x;
    if (i < npad) bucket[i] = -1;
    if (i < C_NUM * D_H) pooled[i] = 0.f;
    if (i < 256) hr_raw[i] = 0.f;
    if (i < 16) { counts[i] = 0; cursor[i] = 0; scores[i] = 0.f; }
}

__global__ void k_hist(const int* __restrict__ cid, int* counts, int n) {
    int i = blockIdx.x * blockDim.x + threadIdx.x;
    if (i < n) atomicAdd(&counts[cid[i]], 1);
}

__global__ void k_offsets(const int* __restrict__ counts, int* aoff) {
    if (threadIdx.x == 0) {
        int off = 0;
        for (int c = 0; c < C_NUM; ++c) {
            aoff[c] = off;
            off += ((counts[c] + BM - 1) / BM) * BM;
        }
        aoff[C_NUM] = off;
    }
}

__global__ void k_scatter(const int* __restrict__ cid, int* cursor,
                          const int* __restrict__ aoff, int* bucket, int n) {
    int i = blockIdx.x * blockDim.x + threadIdx.x;
    if (i < n) {
        int c = cid[i];
        int pos = atomicAdd(&cursor[c], 1);
        bucket[aoff[c] + pos] = i;
    }
}

// xb[row,:] = bf16(x[bucket[row],:]), zeros for pad rows. 2 rows / block.
__global__ __launch_bounds__(256) void k_convert(const float* __restrict__ x,
                                                 const int* __restrict__ bucket,
                                                 short* __restrict__ xb) {
    int tid = threadIdx.x;
    int row = blockIdx.x * 2 + (tid >> 7);
    int e0 = (tid & 127) * 8;
    int r = bucket[row];
    f32x4 f0 = {0.f, 0.f, 0.f, 0.f}, f1 = {0.f, 0.f, 0.f, 0.f};
    if (r >= 0) {
        const f32x4* p = (const f32x4*)&x[(size_t)r * D_IN + e0];
        f0 = p[0]; f1 = p[1];
    }
    short8v v;
#pragma unroll
    for (int e = 0; e < 4; ++e) { v[e] = f2bf(f0[e]); v[4 + e] = f2bf(f1[e]); }
    *(short8v*)&xb[(size_t)row * D_IN + e0] = v;
}

// W [C][K][N] fp32 -> Wt [C][N][K] bf16.  grid (K/64, N/64, C), block 256.
__global__ __launch_bounds__(256) void k_transpose(const float* __restrict__ W,
                                                   short* __restrict__ Wt, int K, int N) {
    __shared__ float t[64][65];
    int k0 = blockIdx.x * 64, n0 = blockIdx.y * 64, cc = blockIdx.z;
    const float* src = W + (size_t)cc * K * N;
    short* dst = Wt + (size_t)cc * N * K;
    int tid = threadIdx.x;
    int tk = tid >> 4, tn4 = (tid & 15) * 4;
#pragma unroll
    for (int it = 0; it < 4; ++it) {
        int k = tk + it * 16;
        f32x4 v = *(const f32x4*)&src[(size_t)(k0 + k) * N + n0 + tn4];
        t[k][tn4 + 0] = v[0]; t[k][tn4 + 1] = v[1];
        t[k][tn4 + 2] = v[2]; t[k][tn4 + 3] = v[3];
    }
    __syncthreads();
    int wn = tid >> 2, kq = (tid & 3) * 16;
#pragma unroll
    for (int q = 0; q < 4; ++q) {
        int k = kq + q * 4;
        short4v o;
#pragma unroll
        for (int e = 0; e < 4; ++e) o[e] = f2bf(t[k + e][wn]);
        *(short4v*)&dst[(size_t)(n0 + wn) * K + k0 + k] = o;
    }
}

// gemm1 (big-ws path): h1 = relu(xb @ W1t^T + b1), both operands via global_load_lds
__global__ __launch_bounds__(256) void k_gemm1b(
    const short* __restrict__ xb, const short* __restrict__ Wt, const float* __restrict__ b1,
    const int* __restrict__ bucket, const int* __restrict__ aoff, short* __restrict__ h1)
{
    __shared__ short As[BM * BKS];
    __shared__ short Bs[BN * BKS];
    __shared__ int ridx[BM];

    int wg = xcd_swizzle(blockIdx.x, gridDim.x);
    int rowStart = (wg >> 2) * BM;
    if (rowStart >= aoff[C_NUM]) return;
    int c = 0;
    while (c < C_NUM - 1 && rowStart >= aoff[c + 1]) ++c;
    int colStart = (wg & 3) * BN;

    int tid = threadIdx.x;
    int lane = tid & 63;
    int wid = tid >> 6;
    int wm = wid >> 1, wn = wid & 1;

    if (tid < BM) ridx[tid] = bucket[rowStart + tid];

    int l8 = lane >> 3;
    int sslot = (lane & 7) ^ l8;
    const short* abase = xb + (size_t)(rowStart + l8) * D_IN + sslot * 8;
    const short* bbase = Wt + ((size_t)c * D_H + colStart + l8) * D_IN + sslot * 8;

    f32x4 acc[4][4];
#pragma unroll
    for (int i = 0; i < 4; ++i)
#pragma unroll
        for (int j = 0; j < 4; ++j)
            acc[i][j] = f32x4{0.f, 0.f, 0.f, 0.f};

    for (int k0 = 0; k0 < D_IN; k0 += BKS) {
#pragma unroll
        for (int q = 0; q < 4; ++q) {
            int rb = (q * 4 + wid) * 8;
            gload_lds16(abase + (size_t)rb * D_IN + k0, &As[rb * BKS]);
            gload_lds16(bbase + (size_t)rb * D_IN + k0, &Bs[rb * BKS]);
        }
        __syncthreads();
#pragma unroll
        for (int kk = 0; kk < 2; ++kk) {
            short8v af[4], bfr[4];
#pragma unroll
            for (int i = 0; i < 4; ++i) {
                int row = wm * 64 + i * 16 + (lane & 15);
                int slot = (kk * 4 + (lane >> 4)) ^ (row & 7);
                af[i] = *(const short8v*)&As[row * BKS + slot * 8];
            }
#pragma unroll
            for (int j = 0; j < 4; ++j) {
                int nn = wn * 64 + j * 16 + (lane & 15);
                int slot = (kk * 4 + (lane >> 4)) ^ (nn & 7);
                bfr[j] = *(const short8v*)&Bs[nn * BKS + slot * 8];
            }
#pragma unroll
            for (int i = 0; i < 4; ++i)
#pragma unroll
                for (int j = 0; j < 4; ++j)
                    acc[i][j] = __builtin_amdgcn_mfma_f32_16x16x32_bf16(af[i], bfr[j], acc[i][j], 0, 0, 0);
        }
        __syncthreads();
    }

    const float* bias = b1 + c * D_H;
    float bj[4];
#pragma unroll
    for (int j = 0; j < 4; ++j) bj[j] = bias[colStart + wn * 64 + j * 16 + (lane & 15)];
#pragma unroll
    for (int i = 0; i < 4; ++i) {
#pragma unroll
        for (int r = 0; r < 4; ++r) {
            int rowl = wm * 64 + i * 16 + (lane >> 4) * 4 + r;
            bool valid = (ridx[rowl] >= 0);
            size_t gro = (size_t)(rowStart + rowl) * D_H + colStart + wn * 64 + (lane & 15);
#pragma unroll
            for (int j = 0; j < 4; ++j) {
                float v = valid ? fmaxf(acc[i][j][r] + bj[j], 0.f) : 0.f;
                h1[gro + j * 16] = f2bf(v);
            }
        }
    }
}

// gemm1 fallback (small ws): reg-staged fp32 x -> bf16 (R2 path, proven)
__global__ __launch_bounds__(256) void k_gemm1_mfma(
    const float* __restrict__ x, const short* __restrict__ Wt, const float* __restrict__ b1,
    const int* __restrict__ bucket, const int* __restrict__ aoff, short* __restrict__ h1)
{
    __shared__ short As[BM * BKS];
    __shared__ short Bs[BN * BKS];
    __shared__ int ridx[BM];

    int rowStart = blockIdx.x * BM;
    if (rowStart >= aoff[C_NUM]) return;
    int c = 0;
    while (c < C_NUM - 1 && rowStart >= aoff[c + 1]) ++c;
    int colStart = blockIdx.y * BN;

    int tid = threadIdx.x;
    int lane = tid & 63;
    int wid = tid >> 6;
    int wm = wid >> 1, wn = wid & 1;

    if (tid < BM) ridx[tid] = bucket[rowStart + tid];
    __syncthreads();

    int arow = tid >> 1;
    int khalf = tid & 1;
    int agr = ridx[arow];
    const float* aptr = x + (size_t)(agr < 0 ? 0 : agr) * D_IN + khalf * 32;

    int l8 = lane >> 3;
    int sslot = (lane & 7) ^ l8;
    const short* bbase = Wt + ((size_t)c * D_H + colStart + l8) * D_IN + sslot * 8;

    f32x4 acc[4][4];
#pragma unroll
    for (int i = 0; i < 4; ++i)
#pragma unroll
        for (int j = 0; j < 4; ++j)
            acc[i][j] = f32x4{0.f, 0.f, 0.f, 0.f};

    for (int k0 = 0; k0 < D_IN; k0 += BKS) {
#pragma unroll
        for (int q = 0; q < 4; ++q) {
            int nbase = (q * 4 + wid) * 8;
            gload_lds16(bbase + (size_t)nbase * D_IN + k0, &Bs[nbase * BKS]);
        }
        {
            const f32x4* p = (const f32x4*)(aptr + k0);
#pragma unroll
            for (int q = 0; q < 4; ++q) {
                f32x4 f0 = {0.f, 0.f, 0.f, 0.f}, f1 = {0.f, 0.f, 0.f, 0.f};
                if (agr >= 0) { f0 = p[2 * q]; f1 = p[2 * q + 1]; }
                short8v v;
#pragma unroll
                for (int e = 0; e < 4; ++e) { v[e] = f2bf(f0[e]); v[4 + e] = f2bf(f1[e]); }
                int slot = (khalf * 4 + q) ^ (arow & 7);
                *(short8v*)&As[arow * BKS + slot * 8] = v;
            }
        }
        __syncthreads();
#pragma unroll
        for (int kk = 0; kk < 2; ++kk) {
            short8v af[4], bfr[4];
#pragma unroll
            for (int i = 0; i < 4; ++i) {
                int row = wm * 64 + i * 16 + (lane & 15);
                int slot = (kk * 4 + (lane >> 4)) ^ (row & 7);
                af[i] = *(const short8v*)&As[row * BKS + slot * 8];
            }
#pragma unroll
            for (int j = 0; j < 4; ++j) {
                int nn = wn * 64 + j * 16 + (lane & 15);
                int slot = (kk * 4 + (lane >> 4)) ^ (nn & 7);
                bfr[j] = *(const short8v*)&Bs[nn * BKS + slot * 8];
            }
#pragma unroll
            for (int i = 0; i < 4; ++i)
#pragma unroll
                for (int j = 0; j < 4; ++j)
                    acc[i][j] = __builtin_amdgcn_mfma_f32_16x16x32_bf16(af[i], bfr[j], acc[i][j], 0, 0, 0);
        }
        __syncthreads();
    }

    const float* bias = b1 + c * D_H;
    float bj[4];
#pragma unroll
    for (int j = 0; j < 4; ++j) bj[j] = bias[colStart + wn * 64 + j * 16 + (lane & 15)];
#pragma unroll
    for (int i = 0; i < 4; ++i) {
#pragma unroll
        for (int r = 0; r < 4; ++r) {
            int rowl = wm * 64 + i * 16 + (lane >> 4) * 4 + r;
            bool valid = (ridx[rowl] >= 0);
            size_t gro = (size_t)(rowStart + rowl) * D_H + colStart + wn * 64 + (lane & 15);
#pragma unroll
            for (int j = 0; j < 4; ++j) {
                float v = valid ? fmaxf(acc[i][j][r] + bj[j], 0.f) : 0.f;
                h1[gro + j * 16] = f2bf(v);
            }
        }
    }
}

// pooled[c,:] += column-sum over real rows of relu(h1 @ W2[c] + b2[c])
__global__ __launch_bounds__(256) void k_gemm2_mfma(
    const short* __restrict__ h1, const short* __restrict__ Wt, const float* __restrict__ b2,
    const int* __restrict__ bucket, const int* __restrict__ aoff, float* __restrict__ pooled)
{
    __shared__ short As[BM * BKS];
    __shared__ short Bs[BN * BKS];
    __shared__ int ridx[BM];

    int wg = xcd_swizzle(blockIdx.x, gridDim.x);
    int rowStart = (wg >> 2) * BM;
    if (rowStart >= aoff[C_NUM]) return;
    int c = 0;
    while (c < C_NUM - 1 && rowStart >= aoff[c + 1]) ++c;
    int colStart = (wg & 3) * BN;

    int tid = threadIdx.x;
    int lane = tid & 63;
    int wid = tid >> 6;
    int wm = wid >> 1, wn = wid & 1;

    if (tid < BM) ridx[tid] = bucket[rowStart + tid];

    int l8 = lane >> 3;
    int sslot = (lane & 7) ^ l8;
    const short* abase = h1 + (size_t)(rowStart + l8) * D_H + sslot * 8;
    const short* bbase = Wt + ((size_t)c * D_H + colStart + l8) * D_H + sslot * 8;

    f32x4 acc[4][4];
#pragma unroll
    for (int i = 0; i < 4; ++i)
#pragma unroll
        for (int j = 0; j < 4; ++j)
            acc[i][j] = f32x4{0.f, 0.f, 0.f, 0.f};

    for (int k0 = 0; k0 < D_H; k0 += BKS) {
#pragma unroll
        for (int q = 0; q < 4; ++q) {
            int rb = (q * 4 + wid) * 8;
            gload_lds16(abase + (size_t)rb * D_H + k0, &As[rb * BKS]);
            gload_lds16(bbase + (size_t)rb * D_H + k0, &Bs[rb * BKS]);
        }
        __syncthreads();
#pragma unroll
        for (int kk = 0; kk < 2; ++kk) {
            short8v af[4], bfr[4];
#pragma unroll
            for (int i = 0; i < 4; ++i) {
                int row = wm * 64 + i * 16 + (lane & 15);
                int slot = (kk * 4 + (lane >> 4)) ^ (row & 7);
                af[i] = *(const short8v*)&As[row * BKS + slot * 8];
            }
#pragma unroll
            for (int j = 0; j < 4; ++j) {
                int nn = wn * 64 + j * 16 + (lane & 15);
                int slot = (kk * 4 + (lane >> 4)) ^ (nn & 7);
                bfr[j] = *(const short8v*)&Bs[nn * BKS + slot * 8];
            }
#pragma unroll
            for (int i = 0; i < 4; ++i)
#pragma unroll
                for (int j = 0; j < 4; ++j)
                    acc[i][j] = __builtin_amdgcn_mfma_f32_16x16x32_bf16(af[i], bfr[j], acc[i][j], 0, 0, 0);
        }
        __syncthreads();
    }

    const float* bias = b2 + c * D_H;
    float bj[4];
#pragma unroll
    for (int j = 0; j < 4; ++j) bj[j] = bias[colStart + wn * 64 + j * 16 + (lane & 15)];
    float csum[4] = {0.f, 0.f, 0.f, 0.f};
#pragma unroll
    for (int i = 0; i < 4; ++i) {
#pragma unroll
        for (int r = 0; r < 4; ++r) {
            int rowl = wm * 64 + i * 16 + (lane >> 4) * 4 + r;
            float m = (ridx[rowl] >= 0) ? 1.f : 0.f;
#pragma unroll
            for (int j = 0; j < 4; ++j)
                csum[j] += m * fmaxf(acc[i][j][r] + bj[j], 0.f);
        }
    }
#pragma unroll
    for (int j = 0; j < 4; ++j) {
        float s = csum[j];
        s += __shfl_xor(s, 16, 64);
        s += __shfl_xor(s, 32, 64);
        if ((lane >> 4) == 0)
            atomicAdd(&pooled[c * D_H + colStart + wn * 64 + j * 16 + lane], s);
    }
}

// ---- tail stage A: hfc[c][j] = relu(hc[c] @ Wfc[:,j] + bfc[j]) ----
// grid 8 blocks (64 cols each) x 256 threads (64 cols x 4 k-quarters)
__global__ __launch_bounds__(256) void k_tA(
    const float* __restrict__ pooled, const int* __restrict__ counts,
    const float* __restrict__ Wfc, const float* __restrict__ bfc,
    float* __restrict__ hfc)
{
    __shared__ float hcs[C_NUM][D_H];
    __shared__ float red[4][64][C_NUM];
    int tid = threadIdx.x;
    for (int idx = tid; idx < C_NUM * D_H; idx += 256) {
        int cc = idx >> 9;
        hcs[cc][idx & (D_H - 1)] = pooled[idx] / fmaxf((float)counts[cc], 1.f);
    }
    __syncthreads();
    int col = blockIdx.x * 64 + (tid & 63);
    int kq = tid >> 6, k0 = kq * 128;
    float acc[C_NUM] = {};
    for (int k = 0; k < 128; ++k) {
        float wv = Wfc[(size_t)(k0 + k) * D_H + col];
#pragma unroll
        for (int cc = 0; cc < C_NUM; ++cc) acc[cc] += hcs[cc][k0 + k] * wv;
    }
#pragma unroll
    for (int cc = 0; cc < C_NUM; ++cc) red[kq][tid & 63][cc] = acc[cc];
    __syncthreads();
    if (kq == 0) {
        float bv = bfc[col];
#pragma unroll
        for (int cc = 0; cc < C_NUM; ++cc) {
            float s = red[0][tid][cc] + red[1][tid][cc] + red[2][tid][cc] + red[3][tid][cc];
            hfc[cc * D_H + col] = fmaxf(s + bv, 0.f);
        }
    }
}

// ---- tail stage B: scores[c] += sum_ad tanh(.)*sigmoid(.)*Wc[ad] ----
// grid 4 blocks (64 att-dims each) x 256 threads (64 ad x 4 k-quarters)
__global__ __launch_bounds__(256) void k_tB(
    const float* __restrict__ hfc,
    const float* __restrict__ Wa, const float* __restrict__ ba,
    const float* __restrict__ Wb, const float* __restrict__ bb,
    const float* __restrict__ Wc,
    float* __restrict__ scores)
{
    __shared__ float hfs[C_NUM][D_H];
    __shared__ float red[4][64][C_NUM][2];
    int tid = threadIdx.x;
    for (int idx = tid; idx < C_NUM * D_H; idx += 256) {
        hfs[idx >> 9][idx & (D_H - 1)] = hfc[idx];
    }
    __syncthreads();
    int ad = blockIdx.x * 64 + (tid & 63);
    int kq = tid >> 6, k0 = kq * 128;
    float sa[C_NUM] = {}, sb[C_NUM] = {};
    for (int k = 0; k < 128; ++k) {
        float wav = Wa[(size_t)(k0 + k) * D_ATT + ad];
        float wbv = Wb[(size_t)(k0 + k) * D_ATT + ad];
#pragma unroll
        for (int cc = 0; cc < C_NUM; ++cc) {
            float h = hfs[cc][k0 + k];
            sa[cc] += h * wav;
            sb[cc] += h * wbv;
        }
    }
#pragma unroll
    for (int cc = 0; cc < C_NUM; ++cc) {
        red[kq][tid & 63][cc][0] = sa[cc];
        red[kq][tid & 63][cc][1] = sb[cc];
    }
    __syncthreads();
    if (kq == 0) {  // tid 0..63 = wave 0
        float bav = ba[ad], bbv = bb[ad], wcv = Wc[ad];
#pragma unroll
        for (int cc = 0; cc < C_NUM; ++cc) {
            float sat = red[0][tid][cc][0] + red[1][tid][cc][0] + red[2][tid][cc][0] + red[3][tid][cc][0];
            float sbt = red[0][tid][cc][1] + red[1][tid][cc][1] + red[2][tid][cc][1] + red[3][tid][cc][1];
            float v = tanhf(sat + bav) * (1.f / (1.f + expf(-(sbt + bbv)))) * wcv;
            v += __shfl_xor(v, 1, 64); v += __shfl_xor(v, 2, 64); v += __shfl_xor(v, 4, 64);
            v += __shfl_xor(v, 8, 64); v += __shfl_xor(v, 16, 64); v += __shfl_xor(v, 32, 64);
            if (tid == 0) atomicAdd(&scores[cc], v);
        }
    }
}

// ---- tail stage C: softmax over clusters, hp = A @ hfc ----
__global__ __launch_bounds__(512) void k_tC(
    const float* __restrict__ scores, const float* __restrict__ bc,
    const float* __restrict__ hfc, float* __restrict__ hp)
{
    __shared__ float sA[C_NUM];
    int tid = threadIdx.x;
    if (tid == 0) {
        float sc2[C_NUM];
        float mx = -1e30f;
#pragma unroll
        for (int cc = 0; cc < C_NUM; ++cc) { sc2[cc] = scores[cc] + bc[0]; mx = fmaxf(mx, sc2[cc]); }
        float sum = 0.f;
#pragma unroll
        for (int cc = 0; cc < C_NUM; ++cc) { sc2[cc] = expf(sc2[cc] - mx); sum += sc2[cc]; }
#pragma unroll
        for (int cc = 0; cc < C_NUM; ++cc) sA[cc] = sc2[cc] / sum;
    }
    __syncthreads();
    float s = 0.f;
#pragma unroll
    for (int cc = 0; cc < C_NUM; ++cc) s += sA[cc] * hfc[cc * D_H + tid];
    hp[tid] = s;
}

// ---- tail stage D: hr_raw[j] += sum_{k in block range} hp[k]*Wrho[k][j] ----
// grid 4 blocks (128 k each) x 256 threads (one per output j)
__global__ __launch_bounds__(256) void k_tD(
    const float* __restrict__ hp, const float* __restrict__ Wrho,
    float* __restrict__ hr_raw)
{
    __shared__ float hps[128];
    int tid = threadIdx.x;
    int k0 = blockIdx.x * 128;
    if (tid < 128) hps[tid] = hp[k0 + tid];
    __syncthreads();
    float acc = 0.f;
    for (int k = 0; k < 128; ++k)
        acc += hps[k] * Wrho[(size_t)(k0 + k) * D_ATT + tid];
    atomicAdd(&hr_raw[tid], acc);
}

// ---- tail stage E: rho bias+relu, classifier, hazards/S/argmax ----
__global__ __launch_bounds__(256) void k_tE(
    const float* __restrict__ hr_raw, const float* __restrict__ brho,
    const float* __restrict__ Wcls, const float* __restrict__ bcls,
    float* __restrict__ out)
{
    __shared__ float cpart[4][N_CLS];
    int tid = threadIdx.x, lane = tid & 63, w = tid >> 6;
    float h = fmaxf(hr_raw[tid] + brho[tid], 0.f);
    f32x4 wv = *(const f32x4*)&Wcls[tid * N_CLS];
    float v[N_CLS];
#pragma unroll
    for (int l = 0; l < N_CLS; ++l) {
        v[l] = h * wv[l];
        v[l] += __shfl_xor(v[l], 1, 64); v[l] += __shfl_xor(v[l], 2, 64);
        v[l] += __shfl_xor(v[l], 4, 64); v[l] += __shfl_xor(v[l], 8, 64);
        v[l] += __shfl_xor(v[l], 16, 64); v[l] += __shfl_xor(v[l], 32, 64);
    }
    if (lane == 0) {
#pragma unroll
        for (int l = 0; l < N_CLS; ++l) cpart[w][l] = v[l];
    }
    __syncthreads();
    if (tid == 0) {
        float lg[N_CLS];
#pragma unroll
        for (int l = 0; l < N_CLS; ++l)
            lg[l] = cpart[0][l] + cpart[1][l] + cpart[2][l] + cpart[3][l] + bcls[l];
        int best = 0;
#pragma unroll
        for (int l = 1; l < N_CLS; ++l) if (lg[l] > lg[best]) best = l;
        float Sv = 1.f;
#pragma unroll
        for (int l = 0; l < N_CLS; ++l) {
            float hz = 1.f / (1.f + expf(-lg[l]));
            out[l] = hz;
            Sv *= (1.f - hz);
            out[4 + l] = Sv;
        }
        out[8] = (float)best;
    }
}

extern "C" void kernel_launch(void* const* d_in, const int* in_sizes, int n_in,
                              void* d_out, int out_size, void* d_ws, size_t ws_size,
                              hipStream_t stream)
{
    const float* x    = (const float*)d_in[0];
    const int*   cid  = (const int*)d_in[1];
    const float* W1   = (const float*)d_in[2];
    const float* b1   = (const float*)d_in[3];
    const float* W2   = (const float*)d_in[4];
    const float* b2   = (const float*)d_in[5];
    const float* Wfc  = (const float*)d_in[6];
    const float* bfc  = (const float*)d_in[7];
    const float* Wa   = (const float*)d_in[8];
    const float* ba   = (const float*)d_in[9];
    const float* Wb   = (const float*)d_in[10];
    const float* bb   = (const float*)d_in[11];
    const float* Wc   = (const float*)d_in[12];
    const float* bc   = (const float*)d_in[13];
    const float* Wrho = (const float*)d_in[14];
    const float* brho = (const float*)d_in[15];
    const float* Wcls = (const float*)d_in[16];
    const float* bcls = (const float*)d_in[17];
    float* out = (float*)d_out;

    int n = in_sizes[0] / D_IN;                       // 20000
    int rowTiles = (n + BM - 1) / BM + C_NUM;         // worst-case tiles (167)
    int npadMax = rowTiles * BM;

    // workspace layout
    char* w = (char*)d_ws;
    int* counts = (int*)w;                            // 16
    int* cursor = counts + 16;                        // 16
    int* aoff   = counts + 32;                        // 16 (11 used)
    float* scores = (float*)(counts + 64);            // 16
    float* hr_raw = scores + 16;                      // 256
    float* hp     = hr_raw + 256;                     // 512
    float* hfc    = hp + 512;                         // 5120
    float* pooled = hfc + 5120;                       // 5120
    int* bucket   = (int*)(pooled + 5120);            // npadMax
    short* Wt1 = (short*)(bucket + npadMax);          // C*512*1024
    short* Wt2 = Wt1 + (size_t)C_NUM * D_H * D_IN;    // C*512*512
    short* h1  = Wt2 + (size_t)C_NUM * D_H * D_H;     // npadMax*512
    short* xb  = h1 + (size_t)npadMax * D_H;          // npadMax*1024 (big path)
    size_t need_big = (size_t)((char*)(xb + (size_t)npadMax * D_IN) - w);
    bool big = ws_size >= need_big;

    int ib = (npadMax + 255) / 256;
    k_init<<<ib, 256, 0, stream>>>(counts, cursor, bucket, pooled, scores, hr_raw, npadMax);
    int nb = (n + 255) / 256;
    k_hist<<<nb, 256, 0, stream>>>(cid, counts, n);
    k_offsets<<<1, 64, 0, stream>>>(counts, aoff);
    k_scatter<<<nb, 256, 0, stream>>>(cid, cursor, aoff, bucket, n);

    k_transpose<<<dim3(D_IN / 64, D_H / 64, C_NUM), 256, 0, stream>>>(W1, Wt1, D_IN, D_H);
    k_transpose<<<dim3(D_H / 64, D_H / 64, C_NUM), 256, 0, stream>>>(W2, Wt2, D_H, D_H);

    if (big) {
        k_convert<<<npadMax / 2, 256, 0, stream>>>(x, bucket, xb);
        k_gemm1b<<<rowTiles * 4, 256, 0, stream>>>(xb, Wt1, b1, bucket, aoff, h1);
    } else {
        k_gemm1_mfma<<<dim3(rowTiles, 4), 256, 0, stream>>>(x, Wt1, b1, bucket, aoff, h1);
    }
    k_gemm2_mfma<<<rowTiles * 4, 256, 0, stream>>>(h1, Wt2, b2, bucket, aoff, pooled);

    k_tA<<<8, 256, 0, stream>>>(pooled, counts, Wfc, bfc, hfc);
    k_tB<<<4, 256, 0, stream>>>(hfc, Wa, ba, Wb, bb, Wc, scores);
    k_tC<<<1, 512, 0, stream>>>(scores, bc, hfc, hp);
    k_tD<<<4, 256, 0, stream>>>(hp, Wrho, hr_raw);
    k_tE<<<1, 256, 0, stream>>>(hr_raw, brho, Wcls, bcls, out);
}

// Round 4
// 146.331 us; speedup vs baseline: 6.6590x; 1.9615x over previous
//
#include <hip/hip_runtime.h>
#include <hip/hip_bf16.h>
#include <math.h>

// MIL_Cluster_FC round 4:
//  - LDS-aggregated hist + scatter (was 20000 returning global atomics on 10
//    addresses = 69 us; now ~790 block-level atomics)  [Guideline 12]
//  - k_init replaced by two hipMemsetAsync (0x00 header, 0xFF bucket=-1)
//  - GEMM/tail structure unchanged from R3 (proven, absmax 0.0)

#define C_NUM 10
#define D_IN 1024
#define D_H 512
#define D_ATT 256
#define N_CLS 4
#define BM 128
#define BN 128
#define BKS 64

typedef __attribute__((ext_vector_type(8))) short short8v;
typedef __attribute__((ext_vector_type(4))) short short4v;
typedef __attribute__((ext_vector_type(4))) float f32x4;

__device__ __forceinline__ short f2bf(float f) {
    __hip_bfloat16 h = __float2bfloat16(f);
    return *reinterpret_cast<short*>(&h);
}

__device__ __forceinline__ void gload_lds16(const void* g, void* l) {
    __builtin_amdgcn_global_load_lds((const __attribute__((address_space(1))) unsigned int*)g,
                                     (__attribute__((address_space(3))) unsigned int*)l,
                                     16, 0, 0);
}

// bijective XCD-chunked swizzle (m204)
__device__ __forceinline__ int xcd_swizzle(int orig, int nwg) {
    int q = nwg >> 3, r = nwg & 7;
    int xcd = orig & 7, base = orig >> 3;
    return (xcd < r ? xcd * (q + 1) : r * (q + 1) + (xcd - r) * q) + base;
}

// LDS-aggregated histogram: 10 global atomics per block instead of 256
__global__ __launch_bounds__(256) void k_hist(const int* __restrict__ cid, int* counts, int n) {
    __shared__ int lc[C_NUM];
    int tid = threadIdx.x;
    if (tid < C_NUM) lc[tid] = 0;
    __syncthreads();
    int i = blockIdx.x * 256 + tid;
    if (i < n) atomicAdd(&lc[cid[i]], 1);
    __syncthreads();
    if (tid < C_NUM && lc[tid] > 0) atomicAdd(&counts[tid], lc[tid]);
}

__global__ void k_offsets(const int* __restrict__ counts, int* aoff) {
    if (threadIdx.x == 0) {
        int off = 0;
        for (int c = 0; c < C_NUM; ++c) {
            aoff[c] = off;
            off += ((counts[c] + BM - 1) / BM) * BM;
        }
        aoff[C_NUM] = off;
    }
}

// LDS-aggregated scatter: local rank via LDS atomics, one returning global
// atomic per (block, cluster). Order within a cluster is irrelevant (pool-sum).
__global__ __launch_bounds__(256) void k_scatter(const int* __restrict__ cid, int* cursor,
                                                 const int* __restrict__ aoff, int* bucket, int n) {
    __shared__ int lc[C_NUM];
    __shared__ int base[C_NUM];
    int tid = threadIdx.x;
    if (tid < C_NUM) lc[tid] = 0;
    __syncthreads();
    int i = blockIdx.x * 256 + tid;
    int c = 0, lpos = 0;
    bool valid = (i < n);
    if (valid) { c = cid[i]; lpos = atomicAdd(&lc[c], 1); }
    __syncthreads();
    if (tid < C_NUM) base[tid] = (lc[tid] > 0) ? atomicAdd(&cursor[tid], lc[tid]) : 0;
    __syncthreads();
    if (valid) bucket[aoff[c] + base[c] + lpos] = i;
}

// xb[row,:] = bf16(x[bucket[row],:]), zeros for pad rows. 2 rows / block.
__global__ __launch_bounds__(256) void k_convert(const float* __restrict__ x,
                                                 const int* __restrict__ bucket,
                                                 short* __restrict__ xb) {
    int tid = threadIdx.x;
    int row = blockIdx.x * 2 + (tid >> 7);
    int e0 = (tid & 127) * 8;
    int r = bucket[row];
    f32x4 f0 = {0.f, 0.f, 0.f, 0.f}, f1 = {0.f, 0.f, 0.f, 0.f};
    if (r >= 0) {
        const f32x4* p = (const f32x4*)&x[(size_t)r * D_IN + e0];
        f0 = p[0]; f1 = p[1];
    }
    short8v v;
#pragma unroll
    for (int e = 0; e < 4; ++e) { v[e] = f2bf(f0[e]); v[4 + e] = f2bf(f1[e]); }
    *(short8v*)&xb[(size_t)row * D_IN + e0] = v;
}

// W [C][K][N] fp32 -> Wt [C][N][K] bf16.
__global__ __launch_bounds__(256) void k_transpose(const float* __restrict__ W,
                                                   short* __restrict__ Wt, int K, int N) {
    __shared__ float t[64][65];
    int k0 = blockIdx.x * 64, n0 = blockIdx.y * 64, cc = blockIdx.z;
    const float* src = W + (size_t)cc * K * N;
    short* dst = Wt + (size_t)cc * N * K;
    int tid = threadIdx.x;
    int tk = tid >> 4, tn4 = (tid & 15) * 4;
#pragma unroll
    for (int it = 0; it < 4; ++it) {
        int k = tk + it * 16;
        f32x4 v = *(const f32x4*)&src[(size_t)(k0 + k) * N + n0 + tn4];
        t[k][tn4 + 0] = v[0]; t[k][tn4 + 1] = v[1];
        t[k][tn4 + 2] = v[2]; t[k][tn4 + 3] = v[3];
    }
    __syncthreads();
    int wn = tid >> 2, kq = (tid & 3) * 16;
#pragma unroll
    for (int q = 0; q < 4; ++q) {
        int k = kq + q * 4;
        short4v o;
#pragma unroll
        for (int e = 0; e < 4; ++e) o[e] = f2bf(t[k + e][wn]);
        *(short4v*)&dst[(size_t)(n0 + wn) * K + k0 + k] = o;
    }
}

// gemm1 (big-ws path): h1 = relu(xb @ W1t^T + b1)
__global__ __launch_bounds__(256) void k_gemm1b(
    const short* __restrict__ xb, const short* __restrict__ Wt, const float* __restrict__ b1,
    const int* __restrict__ bucket, const int* __restrict__ aoff, short* __restrict__ h1)
{
    __shared__ short As[BM * BKS];
    __shared__ short Bs[BN * BKS];
    __shared__ int ridx[BM];

    int wg = xcd_swizzle(blockIdx.x, gridDim.x);
    int rowStart = (wg >> 2) * BM;
    if (rowStart >= aoff[C_NUM]) return;
    int c = 0;
    while (c < C_NUM - 1 && rowStart >= aoff[c + 1]) ++c;
    int colStart = (wg & 3) * BN;

    int tid = threadIdx.x;
    int lane = tid & 63;
    int wid = tid >> 6;
    int wm = wid >> 1, wn = wid & 1;

    if (tid < BM) ridx[tid] = bucket[rowStart + tid];

    int l8 = lane >> 3;
    int sslot = (lane & 7) ^ l8;
    const short* abase = xb + (size_t)(rowStart + l8) * D_IN + sslot * 8;
    const short* bbase = Wt + ((size_t)c * D_H + colStart + l8) * D_IN + sslot * 8;

    f32x4 acc[4][4];
#pragma unroll
    for (int i = 0; i < 4; ++i)
#pragma unroll
        for (int j = 0; j < 4; ++j)
            acc[i][j] = f32x4{0.f, 0.f, 0.f, 0.f};

    for (int k0 = 0; k0 < D_IN; k0 += BKS) {
#pragma unroll
        for (int q = 0; q < 4; ++q) {
            int rb = (q * 4 + wid) * 8;
            gload_lds16(abase + (size_t)rb * D_IN + k0, &As[rb * BKS]);
            gload_lds16(bbase + (size_t)rb * D_IN + k0, &Bs[rb * BKS]);
        }
        __syncthreads();
#pragma unroll
        for (int kk = 0; kk < 2; ++kk) {
            short8v af[4], bfr[4];
#pragma unroll
            for (int i = 0; i < 4; ++i) {
                int row = wm * 64 + i * 16 + (lane & 15);
                int slot = (kk * 4 + (lane >> 4)) ^ (row & 7);
                af[i] = *(const short8v*)&As[row * BKS + slot * 8];
            }
#pragma unroll
            for (int j = 0; j < 4; ++j) {
                int nn = wn * 64 + j * 16 + (lane & 15);
                int slot = (kk * 4 + (lane >> 4)) ^ (nn & 7);
                bfr[j] = *(const short8v*)&Bs[nn * BKS + slot * 8];
            }
#pragma unroll
            for (int i = 0; i < 4; ++i)
#pragma unroll
                for (int j = 0; j < 4; ++j)
                    acc[i][j] = __builtin_amdgcn_mfma_f32_16x16x32_bf16(af[i], bfr[j], acc[i][j], 0, 0, 0);
        }
        __syncthreads();
    }

    const float* bias = b1 + c * D_H;
    float bj[4];
#pragma unroll
    for (int j = 0; j < 4; ++j) bj[j] = bias[colStart + wn * 64 + j * 16 + (lane & 15)];
#pragma unroll
    for (int i = 0; i < 4; ++i) {
#pragma unroll
        for (int r = 0; r < 4; ++r) {
            int rowl = wm * 64 + i * 16 + (lane >> 4) * 4 + r;
            bool valid = (ridx[rowl] >= 0);
            size_t gro = (size_t)(rowStart + rowl) * D_H + colStart + wn * 64 + (lane & 15);
#pragma unroll
            for (int j = 0; j < 4; ++j) {
                float v = valid ? fmaxf(acc[i][j][r] + bj[j], 0.f) : 0.f;
                h1[gro + j * 16] = f2bf(v);
            }
        }
    }
}

// gemm1 fallback (small ws): reg-staged fp32 x -> bf16
__global__ __launch_bounds__(256) void k_gemm1_mfma(
    const float* __restrict__ x, const short* __restrict__ Wt, const float* __restrict__ b1,
    const int* __restrict__ bucket, const int* __restrict__ aoff, short* __restrict__ h1)
{
    __shared__ short As[BM * BKS];
    __shared__ short Bs[BN * BKS];
    __shared__ int ridx[BM];

    int rowStart = blockIdx.x * BM;
    if (rowStart >= aoff[C_NUM]) return;
    int c = 0;
    while (c < C_NUM - 1 && rowStart >= aoff[c + 1]) ++c;
    int colStart = blockIdx.y * BN;

    int tid = threadIdx.x;
    int lane = tid & 63;
    int wid = tid >> 6;
    int wm = wid >> 1, wn = wid & 1;

    if (tid < BM) ridx[tid] = bucket[rowStart + tid];
    __syncthreads();

    int arow = tid >> 1;
    int khalf = tid & 1;
    int agr = ridx[arow];
    const float* aptr = x + (size_t)(agr < 0 ? 0 : agr) * D_IN + khalf * 32;

    int l8 = lane >> 3;
    int sslot = (lane & 7) ^ l8;
    const short* bbase = Wt + ((size_t)c * D_H + colStart + l8) * D_IN + sslot * 8;

    f32x4 acc[4][4];
#pragma unroll
    for (int i = 0; i < 4; ++i)
#pragma unroll
        for (int j = 0; j < 4; ++j)
            acc[i][j] = f32x4{0.f, 0.f, 0.f, 0.f};

    for (int k0 = 0; k0 < D_IN; k0 += BKS) {
#pragma unroll
        for (int q = 0; q < 4; ++q) {
            int nbase = (q * 4 + wid) * 8;
            gload_lds16(bbase + (size_t)nbase * D_IN + k0, &Bs[nbase * BKS]);
        }
        {
            const f32x4* p = (const f32x4*)(aptr + k0);
#pragma unroll
            for (int q = 0; q < 4; ++q) {
                f32x4 f0 = {0.f, 0.f, 0.f, 0.f}, f1 = {0.f, 0.f, 0.f, 0.f};
                if (agr >= 0) { f0 = p[2 * q]; f1 = p[2 * q + 1]; }
                short8v v;
#pragma unroll
                for (int e = 0; e < 4; ++e) { v[e] = f2bf(f0[e]); v[4 + e] = f2bf(f1[e]); }
                int slot = (khalf * 4 + q) ^ (arow & 7);
                *(short8v*)&As[arow * BKS + slot * 8] = v;
            }
        }
        __syncthreads();
#pragma unroll
        for (int kk = 0; kk < 2; ++kk) {
            short8v af[4], bfr[4];
#pragma unroll
            for (int i = 0; i < 4; ++i) {
                int row = wm * 64 + i * 16 + (lane & 15);
                int slot = (kk * 4 + (lane >> 4)) ^ (row & 7);
                af[i] = *(const short8v*)&As[row * BKS + slot * 8];
            }
#pragma unroll
            for (int j = 0; j < 4; ++j) {
                int nn = wn * 64 + j * 16 + (lane & 15);
                int slot = (kk * 4 + (lane >> 4)) ^ (nn & 7);
                bfr[j] = *(const short8v*)&Bs[nn * BKS + slot * 8];
            }
#pragma unroll
            for (int i = 0; i < 4; ++i)
#pragma unroll
                for (int j = 0; j < 4; ++j)
                    acc[i][j] = __builtin_amdgcn_mfma_f32_16x16x32_bf16(af[i], bfr[j], acc[i][j], 0, 0, 0);
        }
        __syncthreads();
    }

    const float* bias = b1 + c * D_H;
    float bj[4];
#pragma unroll
    for (int j = 0; j < 4; ++j) bj[j] = bias[colStart + wn * 64 + j * 16 + (lane & 15)];
#pragma unroll
    for (int i = 0; i < 4; ++i) {
#pragma unroll
        for (int r = 0; r < 4; ++r) {
            int rowl = wm * 64 + i * 16 + (lane >> 4) * 4 + r;
            bool valid = (ridx[rowl] >= 0);
            size_t gro = (size_t)(rowStart + rowl) * D_H + colStart + wn * 64 + (lane & 15);
#pragma unroll
            for (int j = 0; j < 4; ++j) {
                float v = valid ? fmaxf(acc[i][j][r] + bj[j], 0.f) : 0.f;
                h1[gro + j * 16] = f2bf(v);
            }
        }
    }
}

// pooled[c,:] += column-sum over real rows of relu(h1 @ W2[c] + b2[c])
__global__ __launch_bounds__(256) void k_gemm2_mfma(
    const short* __restrict__ h1, const short* __restrict__ Wt, const float* __restrict__ b2,
    const int* __restrict__ bucket, const int* __restrict__ aoff, float* __restrict__ pooled)
{
    __shared__ short As[BM * BKS];
    __shared__ short Bs[BN * BKS];
    __shared__ int ridx[BM];

    int wg = xcd_swizzle(blockIdx.x, gridDim.x);
    int rowStart = (wg >> 2) * BM;
    if (rowStart >= aoff[C_NUM]) return;
    int c = 0;
    while (c < C_NUM - 1 && rowStart >= aoff[c + 1]) ++c;
    int colStart = (wg & 3) * BN;

    int tid = threadIdx.x;
    int lane = tid & 63;
    int wid = tid >> 6;
    int wm = wid >> 1, wn = wid & 1;

    if (tid < BM) ridx[tid] = bucket[rowStart + tid];

    int l8 = lane >> 3;
    int sslot = (lane & 7) ^ l8;
    const short* abase = h1 + (size_t)(rowStart + l8) * D_H + sslot * 8;
    const short* bbase = Wt + ((size_t)c * D_H + colStart + l8) * D_H + sslot * 8;

    f32x4 acc[4][4];
#pragma unroll
    for (int i = 0; i < 4; ++i)
#pragma unroll
        for (int j = 0; j < 4; ++j)
            acc[i][j] = f32x4{0.f, 0.f, 0.f, 0.f};

    for (int k0 = 0; k0 < D_H; k0 += BKS) {
#pragma unroll
        for (int q = 0; q < 4; ++q) {
            int rb = (q * 4 + wid) * 8;
            gload_lds16(abase + (size_t)rb * D_H + k0, &As[rb * BKS]);
            gload_lds16(bbase + (size_t)rb * D_H + k0, &Bs[rb * BKS]);
        }
        __syncthreads();
#pragma unroll
        for (int kk = 0; kk < 2; ++kk) {
            short8v af[4], bfr[4];
#pragma unroll
            for (int i = 0; i < 4; ++i) {
                int row = wm * 64 + i * 16 + (lane & 15);
                int slot = (kk * 4 + (lane >> 4)) ^ (row & 7);
                af[i] = *(const short8v*)&As[row * BKS + slot * 8];
            }
#pragma unroll
            for (int j = 0; j < 4; ++j) {
                int nn = wn * 64 + j * 16 + (lane & 15);
                int slot = (kk * 4 + (lane >> 4)) ^ (nn & 7);
                bfr[j] = *(const short8v*)&Bs[nn * BKS + slot * 8];
            }
#pragma unroll
            for (int i = 0; i < 4; ++i)
#pragma unroll
                for (int j = 0; j < 4; ++j)
                    acc[i][j] = __builtin_amdgcn_mfma_f32_16x16x32_bf16(af[i], bfr[j], acc[i][j], 0, 0, 0);
        }
        __syncthreads();
    }

    const float* bias = b2 + c * D_H;
    float bj[4];
#pragma unroll
    for (int j = 0; j < 4; ++j) bj[j] = bias[colStart + wn * 64 + j * 16 + (lane & 15)];
    float csum[4] = {0.f, 0.f, 0.f, 0.f};
#pragma unroll
    for (int i = 0; i < 4; ++i) {
#pragma unroll
        for (int r = 0; r < 4; ++r) {
            int rowl = wm * 64 + i * 16 + (lane >> 4) * 4 + r;
            float m = (ridx[rowl] >= 0) ? 1.f : 0.f;
#pragma unroll
            for (int j = 0; j < 4; ++j)
                csum[j] += m * fmaxf(acc[i][j][r] + bj[j], 0.f);
        }
    }
#pragma unroll
    for (int j = 0; j < 4; ++j) {
        float s = csum[j];
        s += __shfl_xor(s, 16, 64);
        s += __shfl_xor(s, 32, 64);
        if ((lane >> 4) == 0)
            atomicAdd(&pooled[c * D_H + colStart + wn * 64 + j * 16 + lane], s);
    }
}

// ---- tail stage A: hfc[c][j] = relu(hc[c] @ Wfc[:,j] + bfc[j]) ----
__global__ __launch_bounds__(256) void k_tA(
    const float* __restrict__ pooled, const int* __restrict__ counts,
    const float* __restrict__ Wfc, const float* __restrict__ bfc,
    float* __restrict__ hfc)
{
    __shared__ float hcs[C_NUM][D_H];
    __shared__ float red[4][64][C_NUM];
    int tid = threadIdx.x;
    for (int idx = tid; idx < C_NUM * D_H; idx += 256) {
        int cc = idx >> 9;
        hcs[cc][idx & (D_H - 1)] = pooled[idx] / fmaxf((float)counts[cc], 1.f);
    }
    __syncthreads();
    int col = blockIdx.x * 64 + (tid & 63);
    int kq = tid >> 6, k0 = kq * 128;
    float acc[C_NUM] = {};
    for (int k = 0; k < 128; ++k) {
        float wv = Wfc[(size_t)(k0 + k) * D_H + col];
#pragma unroll
        for (int cc = 0; cc < C_NUM; ++cc) acc[cc] += hcs[cc][k0 + k] * wv;
    }
#pragma unroll
    for (int cc = 0; cc < C_NUM; ++cc) red[kq][tid & 63][cc] = acc[cc];
    __syncthreads();
    if (kq == 0) {
        float bv = bfc[col];
#pragma unroll
        for (int cc = 0; cc < C_NUM; ++cc) {
            float s = red[0][tid][cc] + red[1][tid][cc] + red[2][tid][cc] + red[3][tid][cc];
            hfc[cc * D_H + col] = fmaxf(s + bv, 0.f);
        }
    }
}

// ---- tail stage B: scores[c] += sum_ad tanh(.)*sigmoid(.)*Wc[ad] ----
__global__ __launch_bounds__(256) void k_tB(
    const float* __restrict__ hfc,
    const float* __restrict__ Wa, const float* __restrict__ ba,
    const float* __restrict__ Wb, const float* __restrict__ bb,
    const float* __restrict__ Wc,
    float* __restrict__ scores)
{
    __shared__ float hfs[C_NUM][D_H];
    __shared__ float red[4][64][C_NUM][2];
    int tid = threadIdx.x;
    for (int idx = tid; idx < C_NUM * D_H; idx += 256) {
        hfs[idx >> 9][idx & (D_H - 1)] = hfc[idx];
    }
    __syncthreads();
    int ad = blockIdx.x * 64 + (tid & 63);
    int kq = tid >> 6, k0 = kq * 128;
    float sa[C_NUM] = {}, sb[C_NUM] = {};
    for (int k = 0; k < 128; ++k) {
        float wav = Wa[(size_t)(k0 + k) * D_ATT + ad];
        float wbv = Wb[(size_t)(k0 + k) * D_ATT + ad];
#pragma unroll
        for (int cc = 0; cc < C_NUM; ++cc) {
            float h = hfs[cc][k0 + k];
            sa[cc] += h * wav;
            sb[cc] += h * wbv;
        }
    }
#pragma unroll
    for (int cc = 0; cc < C_NUM; ++cc) {
        red[kq][tid & 63][cc][0] = sa[cc];
        red[kq][tid & 63][cc][1] = sb[cc];
    }
    __syncthreads();
    if (kq == 0) {
        float bav = ba[ad], bbv = bb[ad], wcv = Wc[ad];
#pragma unroll
        for (int cc = 0; cc < C_NUM; ++cc) {
            float sat = red[0][tid][cc][0] + red[1][tid][cc][0] + red[2][tid][cc][0] + red[3][tid][cc][0];
            float sbt = red[0][tid][cc][1] + red[1][tid][cc][1] + red[2][tid][cc][1] + red[3][tid][cc][1];
            float v = tanhf(sat + bav) * (1.f / (1.f + expf(-(sbt + bbv)))) * wcv;
            v += __shfl_xor(v, 1, 64); v += __shfl_xor(v, 2, 64); v += __shfl_xor(v, 4, 64);
            v += __shfl_xor(v, 8, 64); v += __shfl_xor(v, 16, 64); v += __shfl_xor(v, 32, 64);
            if (tid == 0) atomicAdd(&scores[cc], v);
        }
    }
}

// ---- tail stage C: softmax over clusters, hp = A @ hfc ----
__global__ __launch_bounds__(512) void k_tC(
    const float* __restrict__ scores, const float* __restrict__ bc,
    const float* __restrict__ hfc, float* __restrict__ hp)
{
    __shared__ float sA[C_NUM];
    int tid = threadIdx.x;
    if (tid == 0) {
        float sc2[C_NUM];
        float mx = -1e30f;
#pragma unroll
        for (int cc = 0; cc < C_NUM; ++cc) { sc2[cc] = scores[cc] + bc[0]; mx = fmaxf(mx, sc2[cc]); }
        float sum = 0.f;
#pragma unroll
        for (int cc = 0; cc < C_NUM; ++cc) { sc2[cc] = expf(sc2[cc] - mx); sum += sc2[cc]; }
#pragma unroll
        for (int cc = 0; cc < C_NUM; ++cc) sA[cc] = sc2[cc] / sum;
    }
    __syncthreads();
    float s = 0.f;
#pragma unroll
    for (int cc = 0; cc < C_NUM; ++cc) s += sA[cc] * hfc[cc * D_H + tid];
    hp[tid] = s;
}

// ---- tail stage D: hr_raw[j] += partial rho ----
__global__ __launch_bounds__(256) void k_tD(
    const float* __restrict__ hp, const float* __restrict__ Wrho,
    float* __restrict__ hr_raw)
{
    __shared__ float hps[128];
    int tid = threadIdx.x;
    int k0 = blockIdx.x * 128;
    if (tid < 128) hps[tid] = hp[k0 + tid];
    __syncthreads();
    float acc = 0.f;
    for (int k = 0; k < 128; ++k)
        acc += hps[k] * Wrho[(size_t)(k0 + k) * D_ATT + tid];
    atomicAdd(&hr_raw[tid], acc);
}

// ---- tail stage E: rho bias+relu, classifier, hazards/S/argmax ----
__global__ __launch_bounds__(256) void k_tE(
    const float* __restrict__ hr_raw, const float* __restrict__ brho,
    const float* __restrict__ Wcls, const float* __restrict__ bcls,
    float* __restrict__ out)
{
    __shared__ float cpart[4][N_CLS];
    int tid = threadIdx.x, lane = tid & 63, w = tid >> 6;
    float h = fmaxf(hr_raw[tid] + brho[tid], 0.f);
    f32x4 wv = *(const f32x4*)&Wcls[tid * N_CLS];
    float v[N_CLS];
#pragma unroll
    for (int l = 0; l < N_CLS; ++l) {
        v[l] = h * wv[l];
        v[l] += __shfl_xor(v[l], 1, 64); v[l] += __shfl_xor(v[l], 2, 64);
        v[l] += __shfl_xor(v[l], 4, 64); v[l] += __shfl_xor(v[l], 8, 64);
        v[l] += __shfl_xor(v[l], 16, 64); v[l] += __shfl_xor(v[l], 32, 64);
    }
    if (lane == 0) {
#pragma unroll
        for (int l = 0; l < N_CLS; ++l) cpart[w][l] = v[l];
    }
    __syncthreads();
    if (tid == 0) {
        float lg[N_CLS];
#pragma unroll
        for (int l = 0; l < N_CLS; ++l)
            lg[l] = cpart[0][l] + cpart[1][l] + cpart[2][l] + cpart[3][l] + bcls[l];
        int best = 0;
#pragma unroll
        for (int l = 1; l < N_CLS; ++l) if (lg[l] > lg[best]) best = l;
        float Sv = 1.f;
#pragma unroll
        for (int l = 0; l < N_CLS; ++l) {
            float hz = 1.f / (1.f + expf(-lg[l]));
            out[l] = hz;
            Sv *= (1.f - hz);
            out[4 + l] = Sv;
        }
        out[8] = (float)best;
    }
}

extern "C" void kernel_launch(void* const* d_in, const int* in_sizes, int n_in,
                              void* d_out, int out_size, void* d_ws, size_t ws_size,
                              hipStream_t stream)
{
    const float* x    = (const float*)d_in[0];
    const int*   cid  = (const int*)d_in[1];
    const float* W1   = (const float*)d_in[2];
    const float* b1   = (const float*)d_in[3];
    const float* W2   = (const float*)d_in[4];
    const float* b2   = (const float*)d_in[5];
    const float* Wfc  = (const float*)d_in[6];
    const float* bfc  = (const float*)d_in[7];
    const float* Wa   = (const float*)d_in[8];
    const float* ba   = (const float*)d_in[9];
    const float* Wb   = (const float*)d_in[10];
    const float* bb   = (const float*)d_in[11];
    const float* Wc   = (const float*)d_in[12];
    const float* bc   = (const float*)d_in[13];
    const float* Wrho = (const float*)d_in[14];
    const float* brho = (const float*)d_in[15];
    const float* Wcls = (const float*)d_in[16];
    const float* bcls = (const float*)d_in[17];
    float* out = (float*)d_out;

    int n = in_sizes[0] / D_IN;                       // 20000
    int rowTiles = (n + BM - 1) / BM + C_NUM;         // worst-case tiles
    int npadMax = rowTiles * BM;

    // workspace layout. Zero-init region first (one memset), then the rest.
    char* w = (char*)d_ws;
    int* counts   = (int*)w;                          // [16]
    int* cursor   = counts + 16;                      // [16]
    float* scores = (float*)(counts + 32);            // [16]
    float* hr_raw = scores + 16;                      // [256]
    float* pooled = hr_raw + 256;                     // [5120]
    size_t zero_bytes = (size_t)(16 + 16 + 16 + 256 + 5120) * 4;
    int* aoff   = (int*)(pooled + 5120);              // [16]
    float* hp   = (float*)(aoff + 16);                // [512]
    float* hfc  = hp + 512;                           // [5120]
    int* bucket = (int*)(hfc + 5120);                 // [npadMax]
    short* Wt1 = (short*)(bucket + npadMax);          // C*512*1024
    short* Wt2 = Wt1 + (size_t)C_NUM * D_H * D_IN;    // C*512*512
    short* h1  = Wt2 + (size_t)C_NUM * D_H * D_H;     // npadMax*512
    short* xb  = h1 + (size_t)npadMax * D_H;          // npadMax*1024 (big path)
    size_t need_big = (size_t)((char*)(xb + (size_t)npadMax * D_IN) - w);
    bool big = ws_size >= need_big;

    hipMemsetAsync(w, 0, zero_bytes, stream);
    hipMemsetAsync(bucket, 0xFF, (size_t)npadMax * 4, stream);  // -1 sentinels

    int nb = (n + 255) / 256;
    k_hist<<<nb, 256, 0, stream>>>(cid, counts, n);
    k_offsets<<<1, 64, 0, stream>>>(counts, aoff);
    k_scatter<<<nb, 256, 0, stream>>>(cid, cursor, aoff, bucket, n);

    k_transpose<<<dim3(D_IN / 64, D_H / 64, C_NUM), 256, 0, stream>>>(W1, Wt1, D_IN, D_H);
    k_transpose<<<dim3(D_H / 64, D_H / 64, C_NUM), 256, 0, stream>>>(W2, Wt2, D_H, D_H);

    if (big) {
        k_convert<<<npadMax / 2, 256, 0, stream>>>(x, bucket, xb);
        k_gemm1b<<<rowTiles * 4, 256, 0, stream>>>(xb, Wt1, b1, bucket, aoff, h1);
    } else {
        k_gemm1_mfma<<<dim3(rowTiles, 4), 256, 0, stream>>>(x, Wt1, b1, bucket, aoff, h1);
    }
    k_gemm2_mfma<<<rowTiles * 4, 256, 0, stream>>>(h1, Wt2, b2, bucket, aoff, pooled);

    k_tA<<<8, 256, 0, stream>>>(pooled, counts, Wfc, bfc, hfc);
    k_tB<<<4, 256, 0, stream>>>(hfc, Wa, ba, Wb, bb, Wc, scores);
    k_tC<<<1, 512, 0, stream>>>(scores, bc, hfc, hp);
    k_tD<<<4, 256, 0, stream>>>(hp, Wrho, hr_raw);
    k_tE<<<1, 256, 0, stream>>>(hr_raw, brho, Wcls, bcls, out);
}